// Round 8
// baseline (26.721 us; speedup 1.0000x reference)
//
#include <hip/hip_runtime.h>

#define B_ 4
#define N_ 256
#define T_ 16
#define F_ 128
#define H_ 256

// ---------------------------------------------------------------------------
// lp_ka: fused prep+gemm. 128 blocks x 1024 threads; block = 8 nodes.
//  1) hbar for 8 nodes -> LDS sh[n][f] (coalesced reads of nodefeat)
//  2) 4 chunks of 64 W1-columns: stage into LDS buf[k][h] transposed
//     (+1-pad row 257), coalesced W1 reads, conflict-free LDS writes;
//     compute: thread (kq 0..3, h 0..255) does 16 k x 8 n FMA per chunk,
//     1 LDS b32 feeds 8 FMA; hbar reads are uniform broadcasts.
//  3) kq-reduction via buf reuse (64 KB union), write:
//       aT[tile4][h][4] (b1 folded), cT[b][h][N]   (same layout as before)
// ---------------------------------------------------------------------------
__global__ __launch_bounds__(1024) void lp_ka(const float* __restrict__ nf,
                                              const float* __restrict__ W1,
                                              const float* __restrict__ b1,
                                              float* __restrict__ aT,
                                              float* __restrict__ cT) {
    __shared__ float sh[8 * 128];    // hbar [n][f]  (4 KB)
    __shared__ float buf[64 * 257];  // union: staged W1T chunk / reduction (65.8 KB)

    const int blk = blockIdx.x;      // 0..127
    const int bn0 = blk * 8;
    const int b   = bn0 >> 8;
    const int n0  = bn0 & 255;
    const int tid = threadIdx.x;

    // ---- 1) time-mean: one (n,f) pair per thread, coalesced over f ----
    {
        const int n = tid >> 7;      // 0..7
        const int f = tid & 127;
        const float* src = nf + (size_t)(bn0 + n) * (T_ * F_) + f;
        float s = 0.f;
#pragma unroll
        for (int t = 0; t < T_; ++t) s += src[t * F_];
        sh[n * 128 + f] = s * (1.0f / 16.0f);
    }

    const int kq = tid >> 8;         // 0..3 (wave-uniform: wave = 64 consec tid)
    const int h  = tid & 255;

    float acca[8] = {0.f, 0.f, 0.f, 0.f, 0.f, 0.f, 0.f, 0.f};
    float accc[8] = {0.f, 0.f, 0.f, 0.f, 0.f, 0.f, 0.f, 0.f};

    // ---- 2) four 64-column chunks of W1 (0,1 -> a-part; 2,3 -> c-part) ----
#pragma unroll
    for (int c = 0; c < 4; ++c) {
        __syncthreads();  // buf reuse boundary (also covers sh writes at c=0)
        // stage: buf[k_local][h] = W1[h][c*64 + k_local], k_local in 0..63
#pragma unroll
        for (int i = 0; i < 4; ++i) {
            const int e  = i * 1024 + tid;  // float4 units: 16 per row x 256 rows
            const int hh = e >> 4;
            const int f4 = e & 15;
            const float4 w = *(const float4*)(W1 + (size_t)hh * 256 + c * 64 + f4 * 4);
            const int k0 = f4 * 4;
            buf[(k0 + 0) * 257 + hh] = w.x;   // banks: (k+h) mod 32 -> conflict-free
            buf[(k0 + 1) * 257 + hh] = w.y;
            buf[(k0 + 2) * 257 + hh] = w.z;
            buf[(k0 + 3) * 257 + hh] = w.w;
        }
        __syncthreads();
        // compute: 16 k per thread, 8 nodes
        const int kb = (c & 1) * 64 + kq * 16;  // hbar k-base (0..127)
        if (c < 2) {
#pragma unroll
            for (int kk = 0; kk < 16; ++kk) {
                const float w = buf[(kq * 16 + kk) * 257 + h];  // lanes=h, conflict-free
                const int kh = kb + kk;                          // uniform
#pragma unroll
                for (int n = 0; n < 8; ++n)
                    acca[n] = fmaf(sh[n * 128 + kh], w, acca[n]);
            }
        } else {
#pragma unroll
            for (int kk = 0; kk < 16; ++kk) {
                const float w = buf[(kq * 16 + kk) * 257 + h];
                const int kh = kb + kk;
#pragma unroll
                for (int n = 0; n < 8; ++n)
                    accc[n] = fmaf(sh[n * 128 + kh], w, accc[n]);
            }
        }
    }

    // ---- 3) kq-reduction: red(v,kq,h) = buf[(v*4+kq)*256 + h] (64 KB) ----
    __syncthreads();
#pragma unroll
    for (int n = 0; n < 8; ++n) {
        buf[((n)     * 4 + kq) * 256 + h] = acca[n];
        buf[((8 + n) * 4 + kq) * 256 + h] = accc[n];
    }
    __syncthreads();

#pragma unroll
    for (int i = 0; i < 4; ++i) {
        const int o  = i * 1024 + tid;  // 16 v x 256 h
        const int v  = o >> 8;
        const int hh = o & 255;
        const float* p = buf + v * 4 * 256 + hh;
        const float s = (p[0] + p[256]) + (p[512] + p[768]);
        if (v < 8) {
            const int bn = bn0 + v;
            aT[((size_t)(bn >> 2) * H_ + hh) * 4 + (bn & 3)] = s + b1[hh];
        } else {
            cT[((size_t)b * H_ + hh) * N_ + (n0 + (v - 8))] = s;
        }
    }
}

// ---------------------------------------------------------------------------
// lp_k2: block = 8 rows x 128 j (grid 256 = 4 b x 32 i-tiles x 2 j-halves)
// 1024 threads = (ho in 0..7 = 32-wide h-chunk, jl in 0..127).
// (round-7 version verbatim)
// ---------------------------------------------------------------------------
__global__ __launch_bounds__(1024) void lp_k2(const float* __restrict__ aT,
                                              const float* __restrict__ cT,
                                              const float* __restrict__ W2,
                                              const float* __restrict__ b2,
                                              float* __restrict__ out) {
    __shared__ float pr[8][8][128];  // [ho][i][jl] = 32 KB

    const int bx  = blockIdx.x;      // 0..255
    const int b   = bx >> 6;         // 0..3
    const int rr  = bx & 63;
    const int it  = rr >> 1;         // 0..31 : i-tile of 8 rows
    const int jh  = rr & 1;          // j half
    const int i0  = it * 8;
    const int j0  = jh * 128;
    const int bn0 = b * N_ + i0;

    const int tid = threadIdx.x;
    const int ho  = __builtin_amdgcn_readfirstlane(tid >> 7);  // 0..7
    const int jl  = tid & 127;

    const float* crow = cT + (size_t)b * (H_ * N_) + j0 + jl;
    const float* a0 = aT + (size_t)(bn0 >> 2) * (H_ * 4);      // uniform base
    const float* a1 = a0 + H_ * 4;
    const int h0 = ho * 32;

    float acc0 = 0.f, acc1 = 0.f, acc2 = 0.f, acc3 = 0.f;
    float acc4 = 0.f, acc5 = 0.f, acc6 = 0.f, acc7 = 0.f;

#pragma unroll 4
    for (int hh = 0; hh < 32; ++hh) {
        const int h = h0 + hh;
        const float  cj  = crow[(size_t)h * N_];           // coalesced over jl
        const float  w   = W2[h];                          // uniform -> s_load
        const float4 av0 = *(const float4*)(a0 + h * 4);   // uniform -> s_load
        const float4 av1 = *(const float4*)(a1 + h * 4);   // uniform -> s_load
        float x;
        x = av0.x + cj; acc0 = fmaf(fmaxf(x, 0.f), w, acc0);
        x = av0.y + cj; acc1 = fmaf(fmaxf(x, 0.f), w, acc1);
        x = av0.z + cj; acc2 = fmaf(fmaxf(x, 0.f), w, acc2);
        x = av0.w + cj; acc3 = fmaf(fmaxf(x, 0.f), w, acc3);
        x = av1.x + cj; acc4 = fmaf(fmaxf(x, 0.f), w, acc4);
        x = av1.y + cj; acc5 = fmaf(fmaxf(x, 0.f), w, acc5);
        x = av1.z + cj; acc6 = fmaf(fmaxf(x, 0.f), w, acc6);
        x = av1.w + cj; acc7 = fmaf(fmaxf(x, 0.f), w, acc7);
    }

    pr[ho][0][jl] = acc0;
    pr[ho][1][jl] = acc1;
    pr[ho][2][jl] = acc2;
    pr[ho][3][jl] = acc3;
    pr[ho][4][jl] = acc4;
    pr[ho][5][jl] = acc5;
    pr[ho][6][jl] = acc6;
    pr[ho][7][jl] = acc7;
    __syncthreads();

    const int oi = tid >> 7;   // 0..7
    const int oj = tid & 127;
    float s = 0.f;
#pragma unroll
    for (int o = 0; o < 8; ++o) s += pr[o][oi][oj];
    out[(size_t)(bn0 + oi) * N_ + j0 + oj] = s + b2[0];
}

extern "C" void kernel_launch(void* const* d_in, const int* in_sizes, int n_in,
                              void* d_out, int out_size, void* d_ws, size_t ws_size,
                              hipStream_t stream) {
    const float* nodefeat = (const float*)d_in[0];  // [B,N,T,F]
    const float* W1       = (const float*)d_in[1];  // [H, 2F]
    const float* b1       = (const float*)d_in[2];  // [H]
    const float* W2       = (const float*)d_in[3];  // [1, H]
    const float* b2       = (const float*)d_in[4];  // [1]
    float* out = (float*)d_out;                     // [B,N,N]

    float* aT = (float*)d_ws;                       // [256 tiles][H][4] = 1 MB
    float* cT = aT + (size_t)256 * H_ * 4;          // [B][H][N]         = 1 MB

    lp_ka<<<128, 1024, 0, stream>>>(nodefeat, W1, b1, aT, cT);
    lp_k2<<<256, 1024, 0, stream>>>(aT, cT, W2, b2, out);
}